// Round 2
// baseline (10022.885 us; speedup 1.0000x reference)
//
#include <hip/hip_runtime.h>
#include <hip/hip_bf16.h>

#define T_ 512
#define B_ 64
#define IN_ 512
#define H_ 1024
#define G4_ 4096

typedef unsigned short u16;
typedef __attribute__((ext_vector_type(8))) short short8;
typedef __attribute__((ext_vector_type(4))) float f32x4;

__device__ __forceinline__ float sigm(float x) { return 1.0f / (1.0f + __expf(-x)); }
__device__ __forceinline__ float ftanh(float x) {
    float e = __expf(-2.0f * fabsf(x));
    float t = (1.0f - e) / (1.0f + e);
    return copysignf(t, x);
}
__device__ __forceinline__ u16 f2bf(float f) {
    unsigned int x = __float_as_uint(f);
    unsigned int r = (x + 0x7FFFu + ((x >> 16) & 1u)) >> 16;
    return (u16)r;
}

// fp32 -> bf16 convert, 4 elems/thread (all n are multiples of 4)
__global__ void f2b_kernel(const float* __restrict__ in, u16* __restrict__ out, int n) {
    int i = (blockIdx.x * blockDim.x + threadIdx.x) * 4;
    if (i < n) {
        float4 v = *reinterpret_cast<const float4*>(in + i);
        out[i + 0] = f2bf(v.x);
        out[i + 1] = f2bf(v.y);
        out[i + 2] = f2bf(v.z);
        out[i + 3] = f2bf(v.w);
    }
}

__global__ void bias_sum_kernel(const float* __restrict__ bih0, const float* __restrict__ bhh0,
                                const float* __restrict__ bih1, const float* __restrict__ bhh1,
                                float* __restrict__ bs0, float* __restrict__ bs1) {
    int i = blockIdx.x * blockDim.x + threadIdx.x;
    if (i < G4_) {
        bs0[i] = bih0[i] + bhh0[i];
        bs1[i] = bih1[i] + bhh1[i];
    }
}

// One pipelined round: layer0 does step t=r, layer1 does step t=r-1.
// grid = (128, 2): blockIdx.x = hidden-unit block (8 units), blockIdx.y = layer.
// block = 256 threads = 4 waves; split-K across waves, LDS reduce, fused pointwise.
// j-tile 8 => 32 W-rows/block (4 gates x 8 hidden) = 2 MFMA B-fragments.
// Fragment f covers cols cc = f*16..f*16+15; cc -> gate g = cc>>3, jl = cc&7.
__global__ __launch_bounds__(256) void lstm_round(
    const u16* __restrict__ in_bf,    // (T,B,IN) bf16
    u16* __restrict__ out0_bf,        // (T,B,H) bf16 (layer0 output / layer1 input)
    const u16* __restrict__ wih0, const u16* __restrict__ whh0,
    const u16* __restrict__ wih1, const u16* __restrict__ whh1,
    const float* __restrict__ bs0, const float* __restrict__ bs1,
    const float* __restrict__ mask,   // (T,B) fp32
    float* __restrict__ hs,           // (2,B,H) fp32 running h
    float* __restrict__ cs,           // (2,B,H) fp32 running c
    u16* __restrict__ hbf,            // (2 layers, 2 bufs, B, H) bf16 h (double-buffered)
    float* __restrict__ dout,         // (T,B,H) fp32 final output (layer1 h)
    int r)
{
    const int layer = blockIdx.y;
    const int t = r - layer;
    if (t < 0 || t >= T_) return;

    const int KIN = layer ? H_ : IN_;
    const u16* xt   = layer ? (out0_bf + (size_t)t * B_ * H_) : (in_bf + (size_t)t * B_ * IN_);
    const u16* Wih  = layer ? wih1 : wih0;
    const u16* Whh  = layer ? whh1 : whh0;
    const float* bsum = layer ? bs1 : bs0;
    float* h_s = hs + layer * B_ * H_;
    float* c_s = cs + layer * B_ * H_;
    const u16* hcur = hbf + ((size_t)(layer * 2 + (t & 1))) * B_ * H_;
    u16* hnxt       = hbf + ((size_t)(layer * 2 + ((t + 1) & 1))) * B_ * H_;

    __shared__ float red[4][64][32];   // [wave][batch][32 W-rows] = 32 KB

    const int tid  = threadIdx.x;
    const int w    = tid >> 6;
    const int lane = tid & 63;
    const int rm   = lane & 15;
    const int ks   = (lane >> 4) << 3;   // k sub-offset 0,8,16,24
    const int j0   = blockIdx.x * 8;

    f32x4 acc[4][2];
    #pragma unroll
    for (int a = 0; a < 4; ++a)
        #pragma unroll
        for (int b = 0; b < 2; ++b)
            acc[a][b] = (f32x4){0.f, 0.f, 0.f, 0.f};

    // B-fragment row index (within-W) for fragment f, lane col rm:
    //   cc = f*16 + rm; gate = cc>>3; jl = cc&7; W-row = gate*H_ + j0 + jl
    int wrow[2];
    #pragma unroll
    for (int f = 0; f < 2; ++f) {
        int cc = f * 16 + rm;
        wrow[f] = (cc >> 3) * H_ + j0 + (cc & 7);
    }

    const int nkk = (KIN + H_) >> 5;   // K_eff/32 : 48 (l0) or 64 (l1)
    for (int kk = w; kk < nkk; kk += 4) {
        const int k0 = kk << 5;
        const u16* ab; int astr; const u16* wb; int wstr;
        if (k0 < KIN) { ab = xt + k0 + ks;           astr = KIN; wb = Wih + k0 + ks;           wstr = KIN; }
        else          { ab = hcur + (k0 - KIN) + ks; astr = H_;  wb = Whh + (k0 - KIN) + ks;  wstr = H_; }

        short8 afr[4], bfr[2];
        #pragma unroll
        for (int mi = 0; mi < 4; ++mi)
            afr[mi] = *reinterpret_cast<const short8*>(ab + (size_t)(mi * 16 + rm) * astr);
        #pragma unroll
        for (int f = 0; f < 2; ++f)
            bfr[f] = *reinterpret_cast<const short8*>(wb + (size_t)wrow[f] * wstr);

        #pragma unroll
        for (int mi = 0; mi < 4; ++mi)
            #pragma unroll
            for (int f = 0; f < 2; ++f)
                acc[mi][f] = __builtin_amdgcn_mfma_f32_16x16x32_bf16(afr[mi], bfr[f], acc[mi][f], 0, 0, 0);
    }

    // C layout (16x16x32): col = lane&15, row = (lane>>4)*4 + reg
    const int rb = (lane >> 4) << 2;
    #pragma unroll
    for (int mi = 0; mi < 4; ++mi)
        #pragma unroll
        for (int f = 0; f < 2; ++f)
            #pragma unroll
            for (int rr = 0; rr < 4; ++rr)
                red[w][mi * 16 + rb + rr][f * 16 + rm] = acc[mi][f][rr];
    __syncthreads();

    const float* mt = mask + (size_t)t * B_;
    #pragma unroll
    for (int q = 0; q < 2; ++q) {
        int u  = tid * 2 + q;      // 0..511
        int b  = u >> 3;           // batch 0..63
        int jl = u & 7;            // hidden within block
        int j  = j0 + jl;
        float pre[4];
        #pragma unroll
        for (int g = 0; g < 4; ++g) {
            int col = g * 8 + jl;  // == (g>>1)*16 + (g&1)*8 + jl
            pre[g] = red[0][b][col] + red[1][b][col] + red[2][b][col] + red[3][b][col]
                   + bsum[g * H_ + j];
        }
        float ig = sigm(pre[0]);
        float fg = sigm(pre[1]);
        float gg = ftanh(pre[2]);
        float og = sigm(pre[3]);
        int idx = b * H_ + j;
        float c_old = c_s[idx];
        float h_old = h_s[idx];
        float mm = mt[b];
        float c_new = fg * c_old + ig * gg;
        float h_new = og * ftanh(c_new);
        h_new = mm * h_new + (1.0f - mm) * h_old;
        c_new = mm * c_new + (1.0f - mm) * c_old;
        c_s[idx] = c_new;
        h_s[idx] = h_new;
        hnxt[idx] = f2bf(h_new);
        if (layer == 0) out0_bf[(size_t)t * B_ * H_ + idx] = f2bf(h_new);
        else            dout[(size_t)t * B_ * H_ + idx] = h_new;
    }
}

__global__ void finalize_kernel(const float* __restrict__ hs, const float* __restrict__ cs,
                                float* __restrict__ dout) {
    int i = blockIdx.x * blockDim.x + threadIdx.x;
    if (i < 2 * B_ * H_) {
        dout[(size_t)T_ * B_ * H_ + i] = hs[i];
        dout[(size_t)T_ * B_ * H_ + 2 * B_ * H_ + i] = cs[i];
    }
}

extern "C" void kernel_launch(void* const* d_in, const int* in_sizes, int n_in,
                              void* d_out, int out_size, void* d_ws, size_t ws_size,
                              hipStream_t stream) {
    const float* input_ = (const float*)d_in[0];
    const float* mask   = (const float*)d_in[1];
    const float* Wih0   = (const float*)d_in[2];
    const float* Whh0   = (const float*)d_in[3];
    const float* bih0   = (const float*)d_in[4];
    const float* bhh0   = (const float*)d_in[5];
    const float* Wih1   = (const float*)d_in[6];
    const float* Whh1   = (const float*)d_in[7];
    const float* bih1   = (const float*)d_in[8];
    const float* bhh1   = (const float*)d_in[9];
    float* dout = (float*)d_out;

    char* ws = (char*)d_ws;
    size_t off = 0;
    auto alloc = [&](size_t bytes) -> void* {
        void* p = ws + off;
        off += (bytes + 255) & ~(size_t)255;
        return p;
    };
    u16* in_bf   = (u16*)alloc((size_t)T_ * B_ * IN_ * 2);
    u16* out0_bf = (u16*)alloc((size_t)T_ * B_ * H_ * 2);
    u16* wih0    = (u16*)alloc((size_t)G4_ * IN_ * 2);
    u16* whh0    = (u16*)alloc((size_t)G4_ * H_ * 2);
    u16* wih1    = (u16*)alloc((size_t)G4_ * H_ * 2);
    u16* whh1    = (u16*)alloc((size_t)G4_ * H_ * 2);
    float* bs0   = (float*)alloc((size_t)G4_ * 4);
    float* bs1   = (float*)alloc((size_t)G4_ * 4);
    float* hs    = (float*)alloc((size_t)2 * B_ * H_ * 4);
    float* cs    = (float*)alloc((size_t)2 * B_ * H_ * 4);
    u16* hbf     = (u16*)alloc((size_t)4 * B_ * H_ * 2);

    // zero the recurrent state (ws is poisoned 0xAA before every launch)
    hipMemsetAsync(hs,  0, (size_t)2 * B_ * H_ * 4, stream);
    hipMemsetAsync(cs,  0, (size_t)2 * B_ * H_ * 4, stream);
    hipMemsetAsync(hbf, 0, (size_t)4 * B_ * H_ * 2, stream);

    auto cvt = [&](const float* src, u16* dst, size_t n) {
        int blocks = (int)((n / 4 + 255) / 256);
        hipLaunchKernelGGL(f2b_kernel, dim3(blocks), dim3(256), 0, stream, src, dst, (int)n);
    };
    cvt(input_, in_bf, (size_t)T_ * B_ * IN_);
    cvt(Wih0, wih0, (size_t)G4_ * IN_);
    cvt(Whh0, whh0, (size_t)G4_ * H_);
    cvt(Wih1, wih1, (size_t)G4_ * H_);
    cvt(Whh1, whh1, (size_t)G4_ * H_);
    hipLaunchKernelGGL(bias_sum_kernel, dim3(16), dim3(256), 0, stream,
                       bih0, bhh0, bih1, bhh1, bs0, bs1);

    for (int r = 0; r <= T_; ++r) {
        hipLaunchKernelGGL(lstm_round, dim3(128, 2), dim3(256), 0, stream,
                           in_bf, out0_bf, wih0, whh0, wih1, whh1, bs0, bs1, mask,
                           hs, cs, hbf, dout, r);
    }
    hipLaunchKernelGGL(finalize_kernel, dim3((2 * B_ * H_ + 255) / 256), dim3(256), 0, stream,
                       hs, cs, dout);
}